// Round 1
// baseline (783.968 us; speedup 1.0000x reference)
//
#include <hip/hip_runtime.h>
#include <math.h>

#define NPTS 4096
#define KNN 10

// ---------------- LAPACK building blocks (f32, faithful to netlib) ----------

__device__ __forceinline__ float slapy2_(float x, float y) {
    float ax = fabsf(x), ay = fabsf(y);
    float w = fmaxf(ax, ay), z = fminf(ax, ay);
    if (z == 0.f) return w;
    float t = z / w;
    return w * sqrtf(1.f + t * t);
}

// LAPACK >= 3.10 slartg convention: c >= 0, r = sign(f)*d, s = g/r
__device__ __forceinline__ void slartg_(float f, float g, float* c, float* s, float* r) {
    if (g == 0.f) { *c = 1.f; *s = 0.f; *r = f; }
    else if (f == 0.f) { *c = 0.f; *s = copysignf(1.f, g); *r = fabsf(g); }
    else {
        float f1 = fabsf(f);
        float d = sqrtf(f * f + g * g);
        float rr = copysignf(d, f);
        *c = f1 / d;
        *s = g / rr;
        *r = rr;
    }
}

__device__ void slaev2_(float a, float b, float c,
                        float* rt1, float* rt2, float* cs1, float* sn1) {
    float sm = a + c;
    float df = a - c;
    float adf = fabsf(df);
    float tb = b + b;
    float ab = fabsf(tb);
    float acmx, acmn;
    if (fabsf(a) > fabsf(c)) { acmx = a; acmn = c; } else { acmx = c; acmn = a; }
    float rt;
    if (adf > ab)      { float t = ab / adf; rt = adf * sqrtf(1.f + t * t); }
    else if (adf < ab) { float t = adf / ab; rt = ab * sqrtf(1.f + t * t); }
    else               { rt = ab * sqrtf(2.f); }
    int sgn1;
    if (sm < 0.f) {
        *rt1 = 0.5f * (sm - rt); sgn1 = -1;
        *rt2 = (acmx / *rt1) * acmn - (b / *rt1) * b;
    } else if (sm > 0.f) {
        *rt1 = 0.5f * (sm + rt); sgn1 = 1;
        *rt2 = (acmx / *rt1) * acmn - (b / *rt1) * b;
    } else {
        *rt1 = 0.5f * rt; *rt2 = -0.5f * rt; sgn1 = 1;
    }
    int sgn2;
    float cs;
    if (df >= 0.f) { cs = df + rt; sgn2 = 1; } else { cs = df - rt; sgn2 = -1; }
    float acs = fabsf(cs);
    if (acs > ab) {
        float ct = -tb / cs;
        *sn1 = 1.f / sqrtf(1.f + ct * ct);
        *cs1 = ct * (*sn1);
    } else {
        if (ab == 0.f) { *cs1 = 1.f; *sn1 = 0.f; }
        else {
            float tn = -cs / tb;
            *cs1 = 1.f / sqrtf(1.f + tn * tn);
            *sn1 = tn * (*cs1);
        }
    }
    if (sgn1 == sgn2) { float tn = *cs1; *cs1 = -(*sn1); *sn1 = tn; }
}

// ssteqr for n=3, ICOMPZ='I' path (Z must be identity on entry). 1-based
// Fortran indices kept via [i-1]. Scaling branch omitted (anorm ~1e-4..1,
// inside [SSFMIN, SSFMAX] for this data).
__device__ void steqr3_(float* d, float* e, float Z[3][3]) {
    const float eps    = 5.9604644775390625e-8f;  // 2^-24
    const float eps2   = eps * eps;
    const float safmin = 1.17549435e-38f;
    const int n = 3, nm1 = 2;
    const int nmaxit = 90;
    int jtot = 0, l1 = 1;
    int guard = 0;

    while (l1 <= n) {
        if (++guard > 600) break;
        if (l1 > 1) e[l1 - 2] = 0.f;
        int m = n;
        if (l1 <= nm1) {
            for (int mm = l1; mm <= nm1; ++mm) {
                float tst = fabsf(e[mm - 1]);
                if (tst == 0.f) { m = mm; break; }
                if (tst <= (sqrtf(fabsf(d[mm - 1])) * sqrtf(fabsf(d[mm]))) * eps) {
                    e[mm - 1] = 0.f; m = mm; break;
                }
            }
        }
        int l = l1, lsv = l1, lend = m, lendsv = m;
        l1 = m + 1;
        if (lend == l) continue;
        float anorm = 0.f;
        for (int i = l; i <= lend; i++) anorm = fmaxf(anorm, fabsf(d[i - 1]));
        for (int i = l; i <= lend - 1; i++) anorm = fmaxf(anorm, fabsf(e[i - 1]));
        if (anorm == 0.f) continue;
        if (fabsf(d[lend - 1]) < fabsf(d[l - 1])) { lend = lsv; l = lendsv; }

        if (lend > l) {
            // ---- QL iteration ----
            for (;;) {
                if (++guard > 600) return;
                int m2 = lend;
                if (l != lend) {
                    for (int mm = l; mm <= lend - 1; ++mm) {
                        float tst = e[mm - 1] * e[mm - 1];
                        if (tst <= (eps2 * fabsf(d[mm - 1])) * fabsf(d[mm]) + safmin) { m2 = mm; break; }
                    }
                }
                if (m2 < lend) e[m2 - 1] = 0.f;
                float p = d[l - 1];
                if (m2 == l) {
                    d[l - 1] = p; l = l + 1;
                    if (l <= lend) continue;
                    break;
                }
                if (m2 == l + 1) {
                    float rt1, rt2, c, s;
                    slaev2_(d[l - 1], e[l - 1], d[l], &rt1, &rt2, &c, &s);
                    for (int i = 0; i < 3; i++) {         // lasr 'R','V','B', cols L,L+1
                        float t = Z[i][l];
                        Z[i][l]     = c * t - s * Z[i][l - 1];
                        Z[i][l - 1] = s * t + c * Z[i][l - 1];
                    }
                    d[l - 1] = rt1; d[l] = rt2; e[l - 1] = 0.f;
                    l += 2;
                    if (l <= lend) continue;
                    break;
                }
                if (jtot == nmaxit) break;
                jtot++;
                float g = (d[l] - p) / (2.f * e[l - 1]);
                float r = slapy2_(g, 1.f);
                g = d[m2 - 1] - p + e[l - 1] / (g + copysignf(r, g));
                float s = 1.f, c = 1.f;
                p = 0.f;
                float csv[2], snv[2];
                for (int i = m2 - 1; i >= l; --i) {
                    float f = s * e[i - 1];
                    float b = c * e[i - 1];
                    slartg_(g, f, &c, &s, &r);
                    if (i != m2 - 1) e[i] = r;
                    g = d[i] - p;
                    r = (d[i - 1] - g) * s + 2.f * c * b;
                    p = s * r;
                    d[i] = g + p;
                    g = c * r - b;
                    csv[i - l] = c; snv[i - l] = -s;
                }
                int nrot = m2 - l;
                for (int j = nrot; j >= 1; --j) {          // lasr 'R','V','B'
                    float C = csv[j - 1], S = snv[j - 1];
                    for (int i = 0; i < 3; i++) {
                        float t = Z[i][l - 1 + j];
                        Z[i][l - 1 + j] = C * t - S * Z[i][l - 2 + j];
                        Z[i][l - 2 + j] = S * t + C * Z[i][l - 2 + j];
                    }
                }
                d[l - 1] = d[l - 1] - p;
                e[l - 1] = g;
            }
        } else {
            // ---- QR iteration ----
            for (;;) {
                if (++guard > 600) return;
                int m2 = lend;
                if (l != lend) {
                    for (int mm = l; mm >= lend + 1; --mm) {
                        float tst = e[mm - 2] * e[mm - 2];
                        if (tst <= (eps2 * fabsf(d[mm - 1])) * fabsf(d[mm - 2]) + safmin) { m2 = mm; break; }
                    }
                }
                if (m2 > lend) e[m2 - 2] = 0.f;
                float p = d[l - 1];
                if (m2 == l) {
                    d[l - 1] = p; l = l - 1;
                    if (l >= lend) continue;
                    break;
                }
                if (m2 == l - 1) {
                    float rt1, rt2, c, s;
                    slaev2_(d[l - 2], e[l - 2], d[l - 1], &rt1, &rt2, &c, &s);
                    for (int i = 0; i < 3; i++) {          // lasr 'R','V','F', cols L-1,L
                        float t = Z[i][l - 1];
                        Z[i][l - 1] = c * t - s * Z[i][l - 2];
                        Z[i][l - 2] = s * t + c * Z[i][l - 2];
                    }
                    d[l - 2] = rt1; d[l - 1] = rt2; e[l - 2] = 0.f;
                    l -= 2;
                    if (l >= lend) continue;
                    break;
                }
                if (jtot == nmaxit) break;
                jtot++;
                float g = (d[l - 2] - p) / (2.f * e[l - 2]);
                float r = slapy2_(g, 1.f);
                g = d[m2 - 1] - p + e[l - 2] / (g + copysignf(r, g));
                float s = 1.f, c = 1.f;
                p = 0.f;
                float csv[2], snv[2];
                for (int i = m2; i <= l - 1; ++i) {
                    float f = s * e[i - 1];
                    float b = c * e[i - 1];
                    slartg_(g, f, &c, &s, &r);
                    if (i != m2) e[i - 2] = r;
                    g = d[i - 1] - p;
                    r = (d[i] - g) * s + 2.f * c * b;
                    p = s * r;
                    d[i - 1] = g + p;
                    g = c * r - b;
                    csv[i - m2] = c; snv[i - m2] = s;
                }
                int nrot = l - m2;
                for (int j = 1; j <= nrot; ++j) {          // lasr 'R','V','F'
                    float C = csv[j - 1], S = snv[j - 1];
                    for (int i = 0; i < 3; i++) {
                        float t = Z[i][m2 - 1 + j];
                        Z[i][m2 - 1 + j] = C * t - S * Z[i][m2 - 2 + j];
                        Z[i][m2 - 2 + j] = S * t + C * Z[i][m2 - 2 + j];
                    }
                }
                d[l - 1] -= p;
                e[l - 2] = g;
            }
        }
    }
    // final ascending sort with column swaps (steqr ICOMPZ>0 epilogue)
    for (int ii = 2; ii <= n; ++ii) {
        int i = ii - 1, k = i;
        float p = d[i - 1];
        for (int j = ii; j <= n; ++j) {
            if (d[j - 1] < p) { k = j; p = d[j - 1]; }
        }
        if (k != i) {
            d[k - 1] = d[i - 1]; d[i - 1] = p;
            for (int r2 = 0; r2 < 3; r2++) {
                float t = Z[r2][i - 1]; Z[r2][i - 1] = Z[r2][k - 1]; Z[r2][k - 1] = t;
            }
        }
    }
}

// ---------------- per-point normal: kNN -> cov -> sytrd -> steqr -> Q -------

__device__ void compute_normal3(const float4* __restrict__ pts, int qi, float out[3]) {
    float4 q = pts[qi];
    float bd[KNN];
    int   bi[KNN];
#pragma unroll
    for (int s = 0; s < KNN; s++) { bd[s] = 3.4e38f; bi[s] = 0; }
    float worst = 3.4e38f;
    int wslot = 0;
    float sqi = q.w;

#pragma unroll 4
    for (int j = 0; j < NPTS; j++) {
        float4 c = pts[j];                        // all lanes same addr -> LDS broadcast
        float dot = fmaf(q.z, c.z, fmaf(q.y, c.y, q.x * c.x));
        float d2 = (sqi + c.w) - 2.f * dot;       // matches sq_i + sq_j - 2*dot
        if (d2 < worst) {
#pragma unroll
            for (int s = 0; s < KNN; s++) { if (s == wslot) { bd[s] = d2; bi[s] = j; } }
            float w = bd[0]; int ws = 0;
#pragma unroll
            for (int s = 1; s < KNN; s++) { if (bd[s] > w) { w = bd[s]; ws = s; } }
            worst = w; wslot = ws;
        }
    }

    // sort 10 by (d2, idx) ascending -> exactly top_k's neighbor order
#pragma unroll
    for (int a = 0; a < KNN - 1; a++) {
#pragma unroll
        for (int b2 = 0; b2 < KNN - 1 - a; b2++) {
            bool sw = (bd[b2] > bd[b2 + 1]) ||
                      (bd[b2] == bd[b2 + 1] && bi[b2] > bi[b2 + 1]);
            float d_lo = sw ? bd[b2 + 1] : bd[b2];
            float d_hi = sw ? bd[b2] : bd[b2 + 1];
            int   i_lo = sw ? bi[b2 + 1] : bi[b2];
            int   i_hi = sw ? bi[b2] : bi[b2 + 1];
            bd[b2] = d_lo; bd[b2 + 1] = d_hi; bi[b2] = i_lo; bi[b2 + 1] = i_hi;
        }
    }

    float xs[KNN], ys[KNN], zs[KNN];
#pragma unroll
    for (int s = 0; s < KNN; s++) {
        float4 c = pts[bi[s]];
        xs[s] = c.x; ys[s] = c.y; zs[s] = c.z;
    }
    float mx = 0.f, my = 0.f, mz = 0.f;
#pragma unroll
    for (int s = 0; s < KNN; s++) { mx += xs[s]; my += ys[s]; mz += zs[s]; }
    mx /= 10.0f; my /= 10.0f; mz /= 10.0f;

    float c00 = 0.f, c10 = 0.f, c20 = 0.f, c11 = 0.f, c21 = 0.f, c22 = 0.f;
#pragma unroll
    for (int s = 0; s < KNN; s++) {
        float dx = xs[s] - mx, dy = ys[s] - my, dz = zs[s] - mz;
        c00 = fmaf(dx, dx, c00);
        c10 = fmaf(dy, dx, c10);
        c20 = fmaf(dz, dx, c20);
        c11 = fmaf(dy, dy, c11);
        c21 = fmaf(dz, dy, c21);
        c22 = fmaf(dz, dz, c22);
    }
    c00 /= 10.0f; c10 /= 10.0f; c20 /= 10.0f; c11 /= 10.0f; c21 /= 10.0f; c22 /= 10.0f;

    // ---- ssytrd, uplo='L', n=3 (one reflector) ----
    float alpha = c10, x2 = c20;
    float tau, v2, beta;
    float xnorm = fabsf(x2);
    if (xnorm == 0.f) { tau = 0.f; v2 = 0.f; beta = alpha; }
    else {
        beta = -copysignf(slapy2_(alpha, xnorm), alpha);
        tau = (beta - alpha) / beta;
        v2 = x2 / (alpha - beta);
    }
    float d[3], e[2];
    d[0] = c00;
    if (tau != 0.f) {
        float p0 = tau * (c11 + c21 * v2);             // symv (lower)
        float p1 = tau * (c21 + c22 * v2);
        float aw = -0.5f * tau * (p0 + p1 * v2);
        float w0 = p0 + aw;
        float w1 = p1 + aw * v2;
        d[1] = (c11 - w0) - w0;                        // syr2
        e[1] = (c21 - v2 * w0) - w1;
        d[2] = (c22 - v2 * w1) - w1 * v2;
        e[0] = beta;
    } else {
        d[1] = c11; d[2] = c22; e[0] = beta; e[1] = c21;
    }

    // ---- ssteqr('I') ----
    float Z[3][3] = {{1.f, 0.f, 0.f}, {0.f, 1.f, 0.f}, {0.f, 0.f, 1.f}};
    steqr3_(d, e, Z);

    // ---- apply Q = H(1) to column 0 (smallest eigenvalue) ----
    float y0 = Z[0][0], y1 = Z[1][0], y2 = Z[2][0];
    if (tau != 0.f) {
        float t = tau * (y1 + v2 * y2);
        y1 = y1 - t;
        y2 = y2 - t * v2;
    }
    out[0] = y0; out[1] = y1; out[2] = y2;
}

// ---------------- kernels ---------------------------------------------------

extern __shared__ float4 spts[];

__global__ __launch_bounds__(256) void normals_kernel(const float* __restrict__ pred,
                                                      const float* __restrict__ gt,
                                                      float* __restrict__ nrm) {
    int bid = blockIdx.x;
    int cloud = bid >> 7;
    int b = (bid >> 4) & 7;
    int chunk = bid & 15;
    const float* src = (cloud == 0 ? pred : gt) + (size_t)b * 3 * NPTS;
    for (int j = threadIdx.x; j < NPTS; j += 256) {
        float x = src[j], y = src[NPTS + j], z = src[2 * NPTS + j];
        float sq = fmaf(z, z, fmaf(y, y, x * x));
        spts[j] = make_float4(x, y, z, sq);
    }
    __syncthreads();
    int qi = chunk * 256 + threadIdx.x;
    float v[3];
    compute_normal3(spts, qi, v);
    float* dst = nrm + ((size_t)cloud * 8 + b) * 3 * NPTS;   // [cloud][b][comp][n]
    dst[0 * NPTS + qi] = v[0];
    dst[1 * NPTS + qi] = v[1];
    dst[2 * NPTS + qi] = v[2];
}

__global__ __launch_bounds__(256) void loss_kernel(const float* __restrict__ nrm,
                                                   float* __restrict__ out) {
    const int n = 8 * 3 * NPTS;
    const float* a = nrm;
    const float* b = nrm + n;
    float acc = 0.f;
    for (int i = blockIdx.x * 256 + threadIdx.x; i < n; i += gridDim.x * 256) {
        float dd = a[i] - b[i];
        acc = fmaf(dd, dd, acc);
    }
#pragma unroll
    for (int off = 32; off > 0; off >>= 1) acc += __shfl_down(acc, off);
    __shared__ float wsum[4];
    int lane = threadIdx.x & 63, wv = threadIdx.x >> 6;
    if (lane == 0) wsum[wv] = acc;
    __syncthreads();
    if (threadIdx.x == 0) {
        float t = wsum[0] + wsum[1] + wsum[2] + wsum[3];
        atomicAdd(out, t * (1.f / (float)n));
    }
}

// fallback if ws is too small: one block does pred then gt with same LDS
__global__ __launch_bounds__(256) void fused_kernel(const float* __restrict__ pred,
                                                    const float* __restrict__ gt,
                                                    float* __restrict__ out) {
    int bid = blockIdx.x;
    int b = bid >> 4;
    int chunk = bid & 15;
    int qi = chunk * 256 + threadIdx.x;
    float va[3], vb[3];

    const float* src = pred + (size_t)b * 3 * NPTS;
    for (int j = threadIdx.x; j < NPTS; j += 256) {
        float x = src[j], y = src[NPTS + j], z = src[2 * NPTS + j];
        spts[j] = make_float4(x, y, z, fmaf(z, z, fmaf(y, y, x * x)));
    }
    __syncthreads();
    compute_normal3(spts, qi, va);
    __syncthreads();

    src = gt + (size_t)b * 3 * NPTS;
    for (int j = threadIdx.x; j < NPTS; j += 256) {
        float x = src[j], y = src[NPTS + j], z = src[2 * NPTS + j];
        spts[j] = make_float4(x, y, z, fmaf(z, z, fmaf(y, y, x * x)));
    }
    __syncthreads();
    compute_normal3(spts, qi, vb);

    float d0 = va[0] - vb[0], d1 = va[1] - vb[1], d2 = va[2] - vb[2];
    float acc = fmaf(d2, d2, fmaf(d1, d1, d0 * d0));
#pragma unroll
    for (int off = 32; off > 0; off >>= 1) acc += __shfl_down(acc, off);
    __shared__ float wsum[4];
    int lane = threadIdx.x & 63, wv = threadIdx.x >> 6;
    if (lane == 0) wsum[wv] = acc;
    __syncthreads();
    if (threadIdx.x == 0) {
        float t = wsum[0] + wsum[1] + wsum[2] + wsum[3];
        atomicAdd(out, t * (1.f / (float)(8 * 3 * NPTS)));
    }
}

extern "C" void kernel_launch(void* const* d_in, const int* in_sizes, int n_in,
                              void* d_out, int out_size, void* d_ws, size_t ws_size,
                              hipStream_t stream) {
    (void)in_sizes; (void)n_in;
    const float* pred = (const float*)d_in[0];
    const float* gt   = (const float*)d_in[1];
    float* out = (float*)d_out;

    hipMemsetAsync(d_out, 0, (size_t)out_size * sizeof(float), stream);

    size_t need = (size_t)2 * 8 * 3 * NPTS * sizeof(float);   // 768 KB
    if (ws_size >= need) {
        float* nrm = (float*)d_ws;
        hipLaunchKernelGGL(normals_kernel, dim3(256), dim3(256), NPTS * sizeof(float4),
                           stream, pred, gt, nrm);
        hipLaunchKernelGGL(loss_kernel, dim3(96), dim3(256), 0, stream, nrm, out);
    } else {
        hipLaunchKernelGGL(fused_kernel, dim3(128), dim3(256), NPTS * sizeof(float4),
                           stream, pred, gt, out);
    }
}

// Round 2
// 328.680 us; speedup vs baseline: 2.3852x; 2.3852x over previous
//
#include <hip/hip_runtime.h>
#include <math.h>

#define NPTS 4096
#define KNN 10

__device__ __forceinline__ float med3f(float a, float b, float c) {
    return __builtin_amdgcn_fmed3f(a, b, c);
}

// ---------------- LAPACK building blocks (f32, faithful to netlib) ----------

__device__ __forceinline__ float slapy2_(float x, float y) {
    float ax = fabsf(x), ay = fabsf(y);
    float w = fmaxf(ax, ay), z = fminf(ax, ay);
    if (z == 0.f) return w;
    float t = z / w;
    return w * sqrtf(1.f + t * t);
}

// LAPACK >= 3.10 slartg convention: c >= 0, r = sign(f)*d, s = g/r
__device__ __forceinline__ void slartg_(float f, float g, float* c, float* s, float* r) {
    if (g == 0.f) { *c = 1.f; *s = 0.f; *r = f; }
    else if (f == 0.f) { *c = 0.f; *s = copysignf(1.f, g); *r = fabsf(g); }
    else {
        float f1 = fabsf(f);
        float d = sqrtf(f * f + g * g);
        float rr = copysignf(d, f);
        *c = f1 / d;
        *s = g / rr;
        *r = rr;
    }
}

__device__ void slaev2_(float a, float b, float c,
                        float* rt1, float* rt2, float* cs1, float* sn1) {
    float sm = a + c;
    float df = a - c;
    float adf = fabsf(df);
    float tb = b + b;
    float ab = fabsf(tb);
    float acmx, acmn;
    if (fabsf(a) > fabsf(c)) { acmx = a; acmn = c; } else { acmx = c; acmn = a; }
    float rt;
    if (adf > ab)      { float t = ab / adf; rt = adf * sqrtf(1.f + t * t); }
    else if (adf < ab) { float t = adf / ab; rt = ab * sqrtf(1.f + t * t); }
    else               { rt = ab * sqrtf(2.f); }
    int sgn1;
    if (sm < 0.f) {
        *rt1 = 0.5f * (sm - rt); sgn1 = -1;
        *rt2 = (acmx / *rt1) * acmn - (b / *rt1) * b;
    } else if (sm > 0.f) {
        *rt1 = 0.5f * (sm + rt); sgn1 = 1;
        *rt2 = (acmx / *rt1) * acmn - (b / *rt1) * b;
    } else {
        *rt1 = 0.5f * rt; *rt2 = -0.5f * rt; sgn1 = 1;
    }
    int sgn2;
    float cs;
    if (df >= 0.f) { cs = df + rt; sgn2 = 1; } else { cs = df - rt; sgn2 = -1; }
    float acs = fabsf(cs);
    if (acs > ab) {
        float ct = -tb / cs;
        *sn1 = 1.f / sqrtf(1.f + ct * ct);
        *cs1 = ct * (*sn1);
    } else {
        if (ab == 0.f) { *cs1 = 1.f; *sn1 = 0.f; }
        else {
            float tn = -cs / tb;
            *cs1 = 1.f / sqrtf(1.f + tn * tn);
            *sn1 = tn * (*cs1);
        }
    }
    if (sgn1 == sgn2) { float tn = *cs1; *cs1 = -(*sn1); *sn1 = tn; }
}

// ssteqr for n=3, ICOMPZ='I' path (verified bit-exact vs numpy in R1)
__device__ void steqr3_(float* d, float* e, float Z[3][3]) {
    const float eps    = 5.9604644775390625e-8f;  // 2^-24
    const float eps2   = eps * eps;
    const float safmin = 1.17549435e-38f;
    const int n = 3, nm1 = 2;
    const int nmaxit = 90;
    int jtot = 0, l1 = 1;
    int guard = 0;

    while (l1 <= n) {
        if (++guard > 600) break;
        if (l1 > 1) e[l1 - 2] = 0.f;
        int m = n;
        if (l1 <= nm1) {
            for (int mm = l1; mm <= nm1; ++mm) {
                float tst = fabsf(e[mm - 1]);
                if (tst == 0.f) { m = mm; break; }
                if (tst <= (sqrtf(fabsf(d[mm - 1])) * sqrtf(fabsf(d[mm]))) * eps) {
                    e[mm - 1] = 0.f; m = mm; break;
                }
            }
        }
        int l = l1, lsv = l1, lend = m, lendsv = m;
        l1 = m + 1;
        if (lend == l) continue;
        float anorm = 0.f;
        for (int i = l; i <= lend; i++) anorm = fmaxf(anorm, fabsf(d[i - 1]));
        for (int i = l; i <= lend - 1; i++) anorm = fmaxf(anorm, fabsf(e[i - 1]));
        if (anorm == 0.f) continue;
        if (fabsf(d[lend - 1]) < fabsf(d[l - 1])) { lend = lsv; l = lendsv; }

        if (lend > l) {
            for (;;) {
                if (++guard > 600) return;
                int m2 = lend;
                if (l != lend) {
                    for (int mm = l; mm <= lend - 1; ++mm) {
                        float tst = e[mm - 1] * e[mm - 1];
                        if (tst <= (eps2 * fabsf(d[mm - 1])) * fabsf(d[mm]) + safmin) { m2 = mm; break; }
                    }
                }
                if (m2 < lend) e[m2 - 1] = 0.f;
                float p = d[l - 1];
                if (m2 == l) {
                    d[l - 1] = p; l = l + 1;
                    if (l <= lend) continue;
                    break;
                }
                if (m2 == l + 1) {
                    float rt1, rt2, c, s;
                    slaev2_(d[l - 1], e[l - 1], d[l], &rt1, &rt2, &c, &s);
                    for (int i = 0; i < 3; i++) {
                        float t = Z[i][l];
                        Z[i][l]     = c * t - s * Z[i][l - 1];
                        Z[i][l - 1] = s * t + c * Z[i][l - 1];
                    }
                    d[l - 1] = rt1; d[l] = rt2; e[l - 1] = 0.f;
                    l += 2;
                    if (l <= lend) continue;
                    break;
                }
                if (jtot == nmaxit) break;
                jtot++;
                float g = (d[l] - p) / (2.f * e[l - 1]);
                float r = slapy2_(g, 1.f);
                g = d[m2 - 1] - p + e[l - 1] / (g + copysignf(r, g));
                float s = 1.f, c = 1.f;
                p = 0.f;
                float csv[2], snv[2];
                for (int i = m2 - 1; i >= l; --i) {
                    float f = s * e[i - 1];
                    float b = c * e[i - 1];
                    slartg_(g, f, &c, &s, &r);
                    if (i != m2 - 1) e[i] = r;
                    g = d[i] - p;
                    r = (d[i - 1] - g) * s + 2.f * c * b;
                    p = s * r;
                    d[i] = g + p;
                    g = c * r - b;
                    csv[i - l] = c; snv[i - l] = -s;
                }
                int nrot = m2 - l;
                for (int j = nrot; j >= 1; --j) {
                    float C = csv[j - 1], S = snv[j - 1];
                    for (int i = 0; i < 3; i++) {
                        float t = Z[i][l - 1 + j];
                        Z[i][l - 1 + j] = C * t - S * Z[i][l - 2 + j];
                        Z[i][l - 2 + j] = S * t + C * Z[i][l - 2 + j];
                    }
                }
                d[l - 1] = d[l - 1] - p;
                e[l - 1] = g;
            }
        } else {
            for (;;) {
                if (++guard > 600) return;
                int m2 = lend;
                if (l != lend) {
                    for (int mm = l; mm >= lend + 1; --mm) {
                        float tst = e[mm - 2] * e[mm - 2];
                        if (tst <= (eps2 * fabsf(d[mm - 1])) * fabsf(d[mm - 2]) + safmin) { m2 = mm; break; }
                    }
                }
                if (m2 > lend) e[m2 - 2] = 0.f;
                float p = d[l - 1];
                if (m2 == l) {
                    d[l - 1] = p; l = l - 1;
                    if (l >= lend) continue;
                    break;
                }
                if (m2 == l - 1) {
                    float rt1, rt2, c, s;
                    slaev2_(d[l - 2], e[l - 2], d[l - 1], &rt1, &rt2, &c, &s);
                    for (int i = 0; i < 3; i++) {
                        float t = Z[i][l - 1];
                        Z[i][l - 1] = c * t - s * Z[i][l - 2];
                        Z[i][l - 2] = s * t + c * Z[i][l - 2];
                    }
                    d[l - 2] = rt1; d[l - 1] = rt2; e[l - 2] = 0.f;
                    l -= 2;
                    if (l >= lend) continue;
                    break;
                }
                if (jtot == nmaxit) break;
                jtot++;
                float g = (d[l - 2] - p) / (2.f * e[l - 2]);
                float r = slapy2_(g, 1.f);
                g = d[m2 - 1] - p + e[l - 2] / (g + copysignf(r, g));
                float s = 1.f, c = 1.f;
                p = 0.f;
                float csv[2], snv[2];
                for (int i = m2; i <= l - 1; ++i) {
                    float f = s * e[i - 1];
                    float b = c * e[i - 1];
                    slartg_(g, f, &c, &s, &r);
                    if (i != m2) e[i - 2] = r;
                    g = d[i - 1] - p;
                    r = (d[i] - g) * s + 2.f * c * b;
                    p = s * r;
                    d[i - 1] = g + p;
                    g = c * r - b;
                    csv[i - m2] = c; snv[i - m2] = s;
                }
                int nrot = l - m2;
                for (int j = 1; j <= nrot; ++j) {
                    float C = csv[j - 1], S = snv[j - 1];
                    for (int i = 0; i < 3; i++) {
                        float t = Z[i][m2 - 1 + j];
                        Z[i][m2 - 1 + j] = C * t - S * Z[i][m2 - 2 + j];
                        Z[i][m2 - 2 + j] = S * t + C * Z[i][m2 - 2 + j];
                    }
                }
                d[l - 1] -= p;
                e[l - 2] = g;
            }
        }
    }
    for (int ii = 2; ii <= n; ++ii) {
        int i = ii - 1, k = i;
        float p = d[i - 1];
        for (int j = ii; j <= n; ++j) {
            if (d[j - 1] < p) { k = j; p = d[j - 1]; }
        }
        if (k != i) {
            d[k - 1] = d[i - 1]; d[i - 1] = p;
            for (int r2 = 0; r2 < 3; r2++) {
                float t = Z[r2][i - 1]; Z[r2][i - 1] = Z[r2][k - 1]; Z[r2][k - 1] = t;
            }
        }
    }
}

// cov -> sytrd -> steqr -> apply Q. Identical arithmetic to the R1-passing code.
__device__ void eig_normal3(const float xs[KNN], const float ys[KNN], const float zs[KNN],
                            float out[3]) {
    float mx = 0.f, my = 0.f, mz = 0.f;
#pragma unroll
    for (int s = 0; s < KNN; s++) { mx += xs[s]; my += ys[s]; mz += zs[s]; }
    mx /= 10.0f; my /= 10.0f; mz /= 10.0f;

    float c00 = 0.f, c10 = 0.f, c20 = 0.f, c11 = 0.f, c21 = 0.f, c22 = 0.f;
#pragma unroll
    for (int s = 0; s < KNN; s++) {
        float dx = xs[s] - mx, dy = ys[s] - my, dz = zs[s] - mz;
        c00 = fmaf(dx, dx, c00);
        c10 = fmaf(dy, dx, c10);
        c20 = fmaf(dz, dx, c20);
        c11 = fmaf(dy, dy, c11);
        c21 = fmaf(dz, dy, c21);
        c22 = fmaf(dz, dz, c22);
    }
    c00 /= 10.0f; c10 /= 10.0f; c20 /= 10.0f; c11 /= 10.0f; c21 /= 10.0f; c22 /= 10.0f;

    float alpha = c10, x2 = c20;
    float tau, v2, beta;
    float xnorm = fabsf(x2);
    if (xnorm == 0.f) { tau = 0.f; v2 = 0.f; beta = alpha; }
    else {
        beta = -copysignf(slapy2_(alpha, xnorm), alpha);
        tau = (beta - alpha) / beta;
        v2 = x2 / (alpha - beta);
    }
    float d[3], e[2];
    d[0] = c00;
    if (tau != 0.f) {
        float p0 = tau * (c11 + c21 * v2);
        float p1 = tau * (c21 + c22 * v2);
        float aw = -0.5f * tau * (p0 + p1 * v2);
        float w0 = p0 + aw;
        float w1 = p1 + aw * v2;
        d[1] = (c11 - w0) - w0;
        e[1] = (c21 - v2 * w0) - w1;
        d[2] = (c22 - v2 * w1) - w1 * v2;
        e[0] = beta;
    } else {
        d[1] = c11; d[2] = c22; e[0] = beta; e[1] = c21;
    }

    float Z[3][3] = {{1.f, 0.f, 0.f}, {0.f, 1.f, 0.f}, {0.f, 0.f, 1.f}};
    steqr3_(d, e, Z);

    float y0 = Z[0][0], y1 = Z[1][0], y2 = Z[2][0];
    if (tau != 0.f) {
        float t = tau * (y1 + v2 * y2);
        y1 = y1 - t;
        y2 = y2 - t * v2;
    }
    out[0] = y0; out[1] = y1; out[2] = y2;
}

// ---------------- main normals kernel: 4 lanes/query, med3 top-k ------------
// block = 512 threads = 128 queries x 4 parts; grid = 2*8*32 = 512 blocks.
// LDS ~59.9 KB -> 2 blocks/CU -> 16 waves/CU (vs 4 before).

__global__ __launch_bounds__(512, 4) void normals_kernel(const float* __restrict__ pred,
                                                         const float* __restrict__ gt,
                                                         float* __restrict__ nrm) {
    __shared__ float sx[NPTS];
    __shared__ float sy[NPTS];
    __shared__ float sz[NPTS];
    __shared__ uint2 spairs[128 * KNN];
    __shared__ int   scnt[128];

    int tid = threadIdx.x;
    int bid = blockIdx.x;
    int cloud = bid >> 8;
    int b = (bid >> 5) & 7;
    int chunk = bid & 31;

    const float* src = (cloud == 0 ? pred : gt) + (size_t)b * 3 * NPTS;
    for (int j = tid; j < NPTS; j += 512) {
        sx[j] = src[j];
        sy[j] = src[NPTS + j];
        sz[j] = src[2 * NPTS + j];
    }
    if (tid < 128) scnt[tid] = 0;
    __syncthreads();

    int part = tid & 3;
    int ql = tid >> 2;                 // local query 0..127
    int qi = chunk * 128 + ql;         // global point index

    float qx = sx[qi], qy = sy[qi], qz = sz[qi];
    float sqi = fmaf(qz, qz, fmaf(qy, qy, qx * qx));

    // ---- pass 1: exact 10-smallest VALUES over strip j = 4*jj+part --------
    // sorted-descending list; update = 10 independent med3 (unconditional).
    float v[KNN + 1];
#pragma unroll
    for (int s = 0; s < KNN; s++) v[s] = INFINITY;
    v[KNN] = -INFINITY;

#pragma unroll 4
    for (int jj = 0; jj < NPTS / 4; jj++) {
        int j = 4 * jj + part;
        float cx = sx[j], cy = sy[j], cz = sz[j];
        float sqj = fmaf(cz, cz, fmaf(cy, cy, cx * cx));
        float dot = fmaf(qz, cz, fmaf(qy, cy, qx * cx));
        float d2 = (sqi + sqj) - 2.f * dot;
#pragma unroll
        for (int s = 0; s < KNN; s++) v[s] = med3f(d2, v[s], v[s + 1]);
    }

    // ---- merge across the 4 parts (same wave, lanes ql*4+part) -> tau* ----
    // lemma: A,B sorted desc => 10 smallest of union = { min(A_i, B_{9-i}) }
    float c[KNN];
#pragma unroll
    for (int i = 0; i < KNN; i++) c[i] = fminf(v[i], __shfl_xor(v[KNN - 1 - i], 1));
    // re-sort descending (bubble, 45 min/max pairs)
#pragma unroll
    for (int a = 0; a < KNN - 1; a++)
#pragma unroll
        for (int bb = 0; bb < KNN - 1 - a; bb++) {
            float hi = fmaxf(c[bb], c[bb + 1]);
            float lo = fminf(c[bb], c[bb + 1]);
            c[bb] = hi; c[bb + 1] = lo;
        }
    float tau = -INFINITY;
#pragma unroll
    for (int i = 0; i < KNN; i++)
        tau = fmaxf(tau, fminf(c[i], __shfl_xor(c[KNN - 1 - i], 2)));
    // tau == exact 10th-smallest d2 for this query

    // ---- pass 2: collect the 10 indices (d2 <= tau), order fixed later ----
#pragma unroll 4
    for (int jj = 0; jj < NPTS / 4; jj++) {
        int j = 4 * jj + part;
        float cx = sx[j], cy = sy[j], cz = sz[j];
        float sqj = fmaf(cz, cz, fmaf(cy, cy, cx * cx));
        float dot = fmaf(qz, cz, fmaf(qy, cy, qx * cx));
        float d2 = (sqi + sqj) - 2.f * dot;
        if (d2 <= tau) {
            int pos = atomicAdd(&scnt[ql], 1);
            if (pos < KNN) spairs[ql * KNN + pos] = make_uint2(__float_as_uint(d2), (unsigned)j);
        }
    }
    __syncthreads();

    // ---- tail: one thread per query ---------------------------------------
    if (tid < 128) {
        int q = tid;
        float bd[KNN]; int bi[KNN];
#pragma unroll
        for (int s = 0; s < KNN; s++) {
            uint2 p = spairs[q * KNN + s];
            bd[s] = __uint_as_float(p.x);
            bi[s] = (int)p.y;
        }
        // sort by (d2, idx) ascending == jax.lax.top_k order
#pragma unroll
        for (int a = 0; a < KNN - 1; a++)
#pragma unroll
            for (int b2 = 0; b2 < KNN - 1 - a; b2++) {
                bool sw = (bd[b2] > bd[b2 + 1]) ||
                          (bd[b2] == bd[b2 + 1] && bi[b2] > bi[b2 + 1]);
                float d_lo = sw ? bd[b2 + 1] : bd[b2];
                float d_hi = sw ? bd[b2] : bd[b2 + 1];
                int   i_lo = sw ? bi[b2 + 1] : bi[b2];
                int   i_hi = sw ? bi[b2] : bi[b2 + 1];
                bd[b2] = d_lo; bd[b2 + 1] = d_hi; bi[b2] = i_lo; bi[b2 + 1] = i_hi;
            }
        float xs[KNN], ys[KNN], zs[KNN];
#pragma unroll
        for (int s = 0; s < KNN; s++) {
            int j = bi[s];
            xs[s] = sx[j]; ys[s] = sy[j]; zs[s] = sz[j];
        }
        float nv[3];
        eig_normal3(xs, ys, zs, nv);
        int qg = chunk * 128 + q;
        float* dst = nrm + ((size_t)cloud * 8 + b) * 3 * NPTS;
        dst[0 * NPTS + qg] = nv[0];
        dst[1 * NPTS + qg] = nv[1];
        dst[2 * NPTS + qg] = nv[2];
    }
}

__global__ __launch_bounds__(256) void loss_kernel(const float* __restrict__ nrm,
                                                   float* __restrict__ out) {
    const int n = 8 * 3 * NPTS;
    const float* a = nrm;
    const float* b = nrm + n;
    float acc = 0.f;
    for (int i = blockIdx.x * 256 + threadIdx.x; i < n; i += gridDim.x * 256) {
        float dd = a[i] - b[i];
        acc = fmaf(dd, dd, acc);
    }
#pragma unroll
    for (int off = 32; off > 0; off >>= 1) acc += __shfl_down(acc, off);
    __shared__ float wsum[4];
    int lane = threadIdx.x & 63, wv = threadIdx.x >> 6;
    if (lane == 0) wsum[wv] = acc;
    __syncthreads();
    if (threadIdx.x == 0) {
        float t = wsum[0] + wsum[1] + wsum[2] + wsum[3];
        atomicAdd(out, t * (1.f / (float)n));
    }
}

// ---------------- fallback (ws too small): R1-verified fused path -----------

extern __shared__ float4 spts_dyn[];

__device__ void compute_normal3(const float4* __restrict__ pts, int qi, float out[3]) {
    float4 q = pts[qi];
    float bd[KNN];
    int   bi[KNN];
#pragma unroll
    for (int s = 0; s < KNN; s++) { bd[s] = 3.4e38f; bi[s] = 0; }
    float worst = 3.4e38f;
    int wslot = 0;
    float sqi = q.w;

#pragma unroll 4
    for (int j = 0; j < NPTS; j++) {
        float4 cc = pts[j];
        float dot = fmaf(q.z, cc.z, fmaf(q.y, cc.y, q.x * cc.x));
        float d2 = (sqi + cc.w) - 2.f * dot;
        if (d2 < worst) {
#pragma unroll
            for (int s = 0; s < KNN; s++) { if (s == wslot) { bd[s] = d2; bi[s] = j; } }
            float w = bd[0]; int ws = 0;
#pragma unroll
            for (int s = 1; s < KNN; s++) { if (bd[s] > w) { w = bd[s]; ws = s; } }
            worst = w; wslot = ws;
        }
    }
#pragma unroll
    for (int a = 0; a < KNN - 1; a++)
#pragma unroll
        for (int b2 = 0; b2 < KNN - 1 - a; b2++) {
            bool sw = (bd[b2] > bd[b2 + 1]) ||
                      (bd[b2] == bd[b2 + 1] && bi[b2] > bi[b2 + 1]);
            float d_lo = sw ? bd[b2 + 1] : bd[b2];
            float d_hi = sw ? bd[b2] : bd[b2 + 1];
            int   i_lo = sw ? bi[b2 + 1] : bi[b2];
            int   i_hi = sw ? bi[b2] : bi[b2 + 1];
            bd[b2] = d_lo; bd[b2 + 1] = d_hi; bi[b2] = i_lo; bi[b2 + 1] = i_hi;
        }
    float xs[KNN], ys[KNN], zs[KNN];
#pragma unroll
    for (int s = 0; s < KNN; s++) {
        float4 cc = pts[bi[s]];
        xs[s] = cc.x; ys[s] = cc.y; zs[s] = cc.z;
    }
    eig_normal3(xs, ys, zs, out);
}

__global__ __launch_bounds__(256) void fused_kernel(const float* __restrict__ pred,
                                                    const float* __restrict__ gt,
                                                    float* __restrict__ out) {
    int bid = blockIdx.x;
    int b = bid >> 4;
    int chunk = bid & 15;
    int qi = chunk * 256 + threadIdx.x;
    float va[3], vb[3];

    const float* src = pred + (size_t)b * 3 * NPTS;
    for (int j = threadIdx.x; j < NPTS; j += 256) {
        float x = src[j], y = src[NPTS + j], z = src[2 * NPTS + j];
        spts_dyn[j] = make_float4(x, y, z, fmaf(z, z, fmaf(y, y, x * x)));
    }
    __syncthreads();
    compute_normal3(spts_dyn, qi, va);
    __syncthreads();

    src = gt + (size_t)b * 3 * NPTS;
    for (int j = threadIdx.x; j < NPTS; j += 256) {
        float x = src[j], y = src[NPTS + j], z = src[2 * NPTS + j];
        spts_dyn[j] = make_float4(x, y, z, fmaf(z, z, fmaf(y, y, x * x)));
    }
    __syncthreads();
    compute_normal3(spts_dyn, qi, vb);

    float d0 = va[0] - vb[0], d1 = va[1] - vb[1], d2 = va[2] - vb[2];
    float acc = fmaf(d2, d2, fmaf(d1, d1, d0 * d0));
#pragma unroll
    for (int off = 32; off > 0; off >>= 1) acc += __shfl_down(acc, off);
    __shared__ float wsum[4];
    int lane = threadIdx.x & 63, wv = threadIdx.x >> 6;
    if (lane == 0) wsum[wv] = acc;
    __syncthreads();
    if (threadIdx.x == 0) {
        float t = wsum[0] + wsum[1] + wsum[2] + wsum[3];
        atomicAdd(out, t * (1.f / (float)(8 * 3 * NPTS)));
    }
}

extern "C" void kernel_launch(void* const* d_in, const int* in_sizes, int n_in,
                              void* d_out, int out_size, void* d_ws, size_t ws_size,
                              hipStream_t stream) {
    (void)in_sizes; (void)n_in;
    const float* pred = (const float*)d_in[0];
    const float* gt   = (const float*)d_in[1];
    float* out = (float*)d_out;

    hipMemsetAsync(d_out, 0, (size_t)out_size * sizeof(float), stream);

    size_t need = (size_t)2 * 8 * 3 * NPTS * sizeof(float);   // 768 KB
    if (ws_size >= need) {
        float* nrm = (float*)d_ws;
        hipLaunchKernelGGL(normals_kernel, dim3(512), dim3(512), 0,
                           stream, pred, gt, nrm);
        hipLaunchKernelGGL(loss_kernel, dim3(96), dim3(256), 0, stream, nrm, out);
    } else {
        hipLaunchKernelGGL(fused_kernel, dim3(128), dim3(256), NPTS * sizeof(float4),
                           stream, pred, gt, out);
    }
}

// Round 3
// 272.050 us; speedup vs baseline: 2.8817x; 1.2082x over previous
//
#include <hip/hip_runtime.h>
#include <math.h>

#define NPTS 4096
#define KNN 10

__device__ __forceinline__ float med3f(float a, float b, float c) {
    return __builtin_amdgcn_fmed3f(a, b, c);
}

// ---------------- LAPACK building blocks (f32, faithful to netlib) ----------

__device__ __forceinline__ float slapy2_(float x, float y) {
    float ax = fabsf(x), ay = fabsf(y);
    float w = fmaxf(ax, ay), z = fminf(ax, ay);
    if (z == 0.f) return w;
    float t = z / w;
    return w * sqrtf(1.f + t * t);
}

// LAPACK >= 3.10 slartg convention: c >= 0, r = sign(f)*d, s = g/r
__device__ __forceinline__ void slartg_(float f, float g, float* c, float* s, float* r) {
    if (g == 0.f) { *c = 1.f; *s = 0.f; *r = f; }
    else if (f == 0.f) { *c = 0.f; *s = copysignf(1.f, g); *r = fabsf(g); }
    else {
        float f1 = fabsf(f);
        float d = sqrtf(f * f + g * g);
        float rr = copysignf(d, f);
        *c = f1 / d;
        *s = g / rr;
        *r = rr;
    }
}

__device__ void slaev2_(float a, float b, float c,
                        float* rt1, float* rt2, float* cs1, float* sn1) {
    float sm = a + c;
    float df = a - c;
    float adf = fabsf(df);
    float tb = b + b;
    float ab = fabsf(tb);
    float acmx, acmn;
    if (fabsf(a) > fabsf(c)) { acmx = a; acmn = c; } else { acmx = c; acmn = a; }
    float rt;
    if (adf > ab)      { float t = ab / adf; rt = adf * sqrtf(1.f + t * t); }
    else if (adf < ab) { float t = adf / ab; rt = ab * sqrtf(1.f + t * t); }
    else               { rt = ab * sqrtf(2.f); }
    int sgn1;
    if (sm < 0.f) {
        *rt1 = 0.5f * (sm - rt); sgn1 = -1;
        *rt2 = (acmx / *rt1) * acmn - (b / *rt1) * b;
    } else if (sm > 0.f) {
        *rt1 = 0.5f * (sm + rt); sgn1 = 1;
        *rt2 = (acmx / *rt1) * acmn - (b / *rt1) * b;
    } else {
        *rt1 = 0.5f * rt; *rt2 = -0.5f * rt; sgn1 = 1;
    }
    int sgn2;
    float cs;
    if (df >= 0.f) { cs = df + rt; sgn2 = 1; } else { cs = df - rt; sgn2 = -1; }
    float acs = fabsf(cs);
    if (acs > ab) {
        float ct = -tb / cs;
        *sn1 = 1.f / sqrtf(1.f + ct * ct);
        *cs1 = ct * (*sn1);
    } else {
        if (ab == 0.f) { *cs1 = 1.f; *sn1 = 0.f; }
        else {
            float tn = -cs / tb;
            *cs1 = 1.f / sqrtf(1.f + tn * tn);
            *sn1 = tn * (*cs1);
        }
    }
    if (sgn1 == sgn2) { float tn = *cs1; *cs1 = -(*sn1); *sn1 = tn; }
}

// ssteqr for n=3, ICOMPZ='I' path (verified bit-exact vs numpy in R1/R2)
__device__ void steqr3_(float* d, float* e, float Z[3][3]) {
    const float eps    = 5.9604644775390625e-8f;  // 2^-24
    const float eps2   = eps * eps;
    const float safmin = 1.17549435e-38f;
    const int n = 3, nm1 = 2;
    const int nmaxit = 90;
    int jtot = 0, l1 = 1;
    int guard = 0;

    while (l1 <= n) {
        if (++guard > 600) break;
        if (l1 > 1) e[l1 - 2] = 0.f;
        int m = n;
        if (l1 <= nm1) {
            for (int mm = l1; mm <= nm1; ++mm) {
                float tst = fabsf(e[mm - 1]);
                if (tst == 0.f) { m = mm; break; }
                if (tst <= (sqrtf(fabsf(d[mm - 1])) * sqrtf(fabsf(d[mm]))) * eps) {
                    e[mm - 1] = 0.f; m = mm; break;
                }
            }
        }
        int l = l1, lsv = l1, lend = m, lendsv = m;
        l1 = m + 1;
        if (lend == l) continue;
        float anorm = 0.f;
        for (int i = l; i <= lend; i++) anorm = fmaxf(anorm, fabsf(d[i - 1]));
        for (int i = l; i <= lend - 1; i++) anorm = fmaxf(anorm, fabsf(e[i - 1]));
        if (anorm == 0.f) continue;
        if (fabsf(d[lend - 1]) < fabsf(d[l - 1])) { lend = lsv; l = lendsv; }

        if (lend > l) {
            for (;;) {
                if (++guard > 600) return;
                int m2 = lend;
                if (l != lend) {
                    for (int mm = l; mm <= lend - 1; ++mm) {
                        float tst = e[mm - 1] * e[mm - 1];
                        if (tst <= (eps2 * fabsf(d[mm - 1])) * fabsf(d[mm]) + safmin) { m2 = mm; break; }
                    }
                }
                if (m2 < lend) e[m2 - 1] = 0.f;
                float p = d[l - 1];
                if (m2 == l) {
                    d[l - 1] = p; l = l + 1;
                    if (l <= lend) continue;
                    break;
                }
                if (m2 == l + 1) {
                    float rt1, rt2, c, s;
                    slaev2_(d[l - 1], e[l - 1], d[l], &rt1, &rt2, &c, &s);
                    for (int i = 0; i < 3; i++) {
                        float t = Z[i][l];
                        Z[i][l]     = c * t - s * Z[i][l - 1];
                        Z[i][l - 1] = s * t + c * Z[i][l - 1];
                    }
                    d[l - 1] = rt1; d[l] = rt2; e[l - 1] = 0.f;
                    l += 2;
                    if (l <= lend) continue;
                    break;
                }
                if (jtot == nmaxit) break;
                jtot++;
                float g = (d[l] - p) / (2.f * e[l - 1]);
                float r = slapy2_(g, 1.f);
                g = d[m2 - 1] - p + e[l - 1] / (g + copysignf(r, g));
                float s = 1.f, c = 1.f;
                p = 0.f;
                float csv[2], snv[2];
                for (int i = m2 - 1; i >= l; --i) {
                    float f = s * e[i - 1];
                    float b = c * e[i - 1];
                    slartg_(g, f, &c, &s, &r);
                    if (i != m2 - 1) e[i] = r;
                    g = d[i] - p;
                    r = (d[i - 1] - g) * s + 2.f * c * b;
                    p = s * r;
                    d[i] = g + p;
                    g = c * r - b;
                    csv[i - l] = c; snv[i - l] = -s;
                }
                int nrot = m2 - l;
                for (int j = nrot; j >= 1; --j) {
                    float C = csv[j - 1], S = snv[j - 1];
                    for (int i = 0; i < 3; i++) {
                        float t = Z[i][l - 1 + j];
                        Z[i][l - 1 + j] = C * t - S * Z[i][l - 2 + j];
                        Z[i][l - 2 + j] = S * t + C * Z[i][l - 2 + j];
                    }
                }
                d[l - 1] = d[l - 1] - p;
                e[l - 1] = g;
            }
        } else {
            for (;;) {
                if (++guard > 600) return;
                int m2 = lend;
                if (l != lend) {
                    for (int mm = l; mm >= lend + 1; --mm) {
                        float tst = e[mm - 2] * e[mm - 2];
                        if (tst <= (eps2 * fabsf(d[mm - 1])) * fabsf(d[mm - 2]) + safmin) { m2 = mm; break; }
                    }
                }
                if (m2 > lend) e[m2 - 2] = 0.f;
                float p = d[l - 1];
                if (m2 == l) {
                    d[l - 1] = p; l = l - 1;
                    if (l >= lend) continue;
                    break;
                }
                if (m2 == l - 1) {
                    float rt1, rt2, c, s;
                    slaev2_(d[l - 2], e[l - 2], d[l - 1], &rt1, &rt2, &c, &s);
                    for (int i = 0; i < 3; i++) {
                        float t = Z[i][l - 1];
                        Z[i][l - 1] = c * t - s * Z[i][l - 2];
                        Z[i][l - 2] = s * t + c * Z[i][l - 2];
                    }
                    d[l - 2] = rt1; d[l - 1] = rt2; e[l - 2] = 0.f;
                    l -= 2;
                    if (l >= lend) continue;
                    break;
                }
                if (jtot == nmaxit) break;
                jtot++;
                float g = (d[l - 2] - p) / (2.f * e[l - 2]);
                float r = slapy2_(g, 1.f);
                g = d[m2 - 1] - p + e[l - 2] / (g + copysignf(r, g));
                float s = 1.f, c = 1.f;
                p = 0.f;
                float csv[2], snv[2];
                for (int i = m2; i <= l - 1; ++i) {
                    float f = s * e[i - 1];
                    float b = c * e[i - 1];
                    slartg_(g, f, &c, &s, &r);
                    if (i != m2) e[i - 2] = r;
                    g = d[i - 1] - p;
                    r = (d[i] - g) * s + 2.f * c * b;
                    p = s * r;
                    d[i - 1] = g + p;
                    g = c * r - b;
                    csv[i - m2] = c; snv[i - m2] = s;
                }
                int nrot = l - m2;
                for (int j = 1; j <= nrot; ++j) {
                    float C = csv[j - 1], S = snv[j - 1];
                    for (int i = 0; i < 3; i++) {
                        float t = Z[i][m2 - 1 + j];
                        Z[i][m2 - 1 + j] = C * t - S * Z[i][m2 - 2 + j];
                        Z[i][m2 - 2 + j] = S * t + C * Z[i][m2 - 2 + j];
                    }
                }
                d[l - 1] -= p;
                e[l - 2] = g;
            }
        }
    }
    for (int ii = 2; ii <= n; ++ii) {
        int i = ii - 1, k = i;
        float p = d[i - 1];
        for (int j = ii; j <= n; ++j) {
            if (d[j - 1] < p) { k = j; p = d[j - 1]; }
        }
        if (k != i) {
            d[k - 1] = d[i - 1]; d[i - 1] = p;
            for (int r2 = 0; r2 < 3; r2++) {
                float t = Z[r2][i - 1]; Z[r2][i - 1] = Z[r2][k - 1]; Z[r2][k - 1] = t;
            }
        }
    }
}

// cov -> sytrd -> steqr -> apply Q. Identical arithmetic to R1/R2-passing code.
__device__ void eig_normal3(const float xs[KNN], const float ys[KNN], const float zs[KNN],
                            float out[3]) {
    float mx = 0.f, my = 0.f, mz = 0.f;
#pragma unroll
    for (int s = 0; s < KNN; s++) { mx += xs[s]; my += ys[s]; mz += zs[s]; }
    mx /= 10.0f; my /= 10.0f; mz /= 10.0f;

    float c00 = 0.f, c10 = 0.f, c20 = 0.f, c11 = 0.f, c21 = 0.f, c22 = 0.f;
#pragma unroll
    for (int s = 0; s < KNN; s++) {
        float dx = xs[s] - mx, dy = ys[s] - my, dz = zs[s] - mz;
        c00 = fmaf(dx, dx, c00);
        c10 = fmaf(dy, dx, c10);
        c20 = fmaf(dz, dx, c20);
        c11 = fmaf(dy, dy, c11);
        c21 = fmaf(dz, dy, c21);
        c22 = fmaf(dz, dz, c22);
    }
    c00 /= 10.0f; c10 /= 10.0f; c20 /= 10.0f; c11 /= 10.0f; c21 /= 10.0f; c22 /= 10.0f;

    float alpha = c10, x2 = c20;
    float tau, v2, beta;
    float xnorm = fabsf(x2);
    if (xnorm == 0.f) { tau = 0.f; v2 = 0.f; beta = alpha; }
    else {
        beta = -copysignf(slapy2_(alpha, xnorm), alpha);
        tau = (beta - alpha) / beta;
        v2 = x2 / (alpha - beta);
    }
    float d[3], e[2];
    d[0] = c00;
    if (tau != 0.f) {
        float p0 = tau * (c11 + c21 * v2);
        float p1 = tau * (c21 + c22 * v2);
        float aw = -0.5f * tau * (p0 + p1 * v2);
        float w0 = p0 + aw;
        float w1 = p1 + aw * v2;
        d[1] = (c11 - w0) - w0;
        e[1] = (c21 - v2 * w0) - w1;
        d[2] = (c22 - v2 * w1) - w1 * v2;
        e[0] = beta;
    } else {
        d[1] = c11; d[2] = c22; e[0] = beta; e[1] = c21;
    }

    float Z[3][3] = {{1.f, 0.f, 0.f}, {0.f, 1.f, 0.f}, {0.f, 0.f, 1.f}};
    steqr3_(d, e, Z);

    float y0 = Z[0][0], y1 = Z[1][0], y2 = Z[2][0];
    if (tau != 0.f) {
        float t = tau * (y1 + v2 * y2);
        y1 = y1 - t;
        y2 = y2 - t * v2;
    }
    out[0] = y0; out[1] = y1; out[2] = y2;
}

// ---------------- main normals kernel: Q=4 queries/thread, 16 parts ---------
// block = 512 threads = 32 query-groups x 16 parts; each thread owns 4 query
// chains over a 256-candidate strip. grid = 2*8*32 = 512 blocks; LDS 59.9 KB
// -> 2 blocks/CU, 16 waves/CU.

__global__ __launch_bounds__(512, 4) void normals_kernel(const float* __restrict__ pred,
                                                         const float* __restrict__ gt,
                                                         float* __restrict__ nrm) {
    __shared__ float sx[NPTS];
    __shared__ float sy[NPTS];
    __shared__ float sz[NPTS];
    __shared__ uint2 spairs[128 * KNN];
    __shared__ int   scnt[128];

    int tid = threadIdx.x;
    int bid = blockIdx.x;
    int cloud = bid >> 8;
    int b = (bid >> 5) & 7;
    int chunk = bid & 31;

    const float* src = (cloud == 0 ? pred : gt) + (size_t)b * 3 * NPTS;
    for (int j = tid; j < NPTS; j += 512) {
        sx[j] = src[j];
        sy[j] = src[NPTS + j];
        sz[j] = src[2 * NPTS + j];
    }
    if (tid < 128) scnt[tid] = 0;
    __syncthreads();

    int part = tid & 15;               // strip id 0..15
    int qg = tid >> 4;                 // query group 0..31
    // this thread's 4 queries: ql = qg*4 + c, global qi = chunk*128 + ql
    int q0 = chunk * 128 + qg * 4;

    float qx[4], qy[4], qz[4], sqi[4];
#pragma unroll
    for (int c = 0; c < 4; c++) {
        int qi = q0 + c;
        qx[c] = sx[qi]; qy[c] = sy[qi]; qz[c] = sz[qi];
        sqi[c] = fmaf(qz[c], qz[c], fmaf(qy[c], qy[c], qx[c] * qx[c]));
    }

    // ---- pass 1: exact 10-smallest values per chain over strip ------------
    float v[4][KNN + 1];
#pragma unroll
    for (int c = 0; c < 4; c++) {
#pragma unroll
        for (int s = 0; s < KNN; s++) v[c][s] = INFINITY;
        v[c][KNN] = -INFINITY;
    }

#pragma unroll 2
    for (int jj = 0; jj < NPTS / 16; jj++) {
        int j = jj * 16 + part;
        float cx = sx[j], cy = sy[j], cz = sz[j];
        float sqj = fmaf(cz, cz, fmaf(cy, cy, cx * cx));
#pragma unroll
        for (int c = 0; c < 4; c++) {
            float dot = fmaf(qz[c], cz, fmaf(qy[c], cy, qx[c] * cx));
            float d2 = (sqi[c] + sqj) - 2.f * dot;
#pragma unroll
            for (int s = 0; s < KNN; s++) v[c][s] = med3f(d2, v[c][s], v[c][s + 1]);
        }
    }

    // ---- merge across the 16 part-lanes (4 xor rounds per chain) ----------
    // lemma: A,B sorted desc => 10 smallest of union = { min(A_i, B_{9-i}) },
    // then re-sort descending. After the rounds all 16 lanes hold the exact
    // merged top-10; tau = element [0] (largest kept = 10th smallest).
    float tau[4];
#pragma unroll
    for (int c = 0; c < 4; c++) {
#pragma unroll
        for (int off = 1; off <= 8; off <<= 1) {
            float t[KNN];
#pragma unroll
            for (int i = 0; i < KNN; i++)
                t[i] = fminf(v[c][i], __shfl_xor(v[c][KNN - 1 - i], off));
#pragma unroll
            for (int a = 0; a < KNN - 1; a++)
#pragma unroll
                for (int bb = 0; bb < KNN - 1 - a; bb++) {
                    float hi = fmaxf(t[bb], t[bb + 1]);
                    float lo = fminf(t[bb], t[bb + 1]);
                    t[bb] = hi; t[bb + 1] = lo;
                }
#pragma unroll
            for (int i = 0; i < KNN; i++) v[c][i] = t[i];
        }
        tau[c] = v[c][0];
    }

    // ---- pass 2: collect indices with d2 <= tau ---------------------------
#pragma unroll 2
    for (int jj = 0; jj < NPTS / 16; jj++) {
        int j = jj * 16 + part;
        float cx = sx[j], cy = sy[j], cz = sz[j];
        float sqj = fmaf(cz, cz, fmaf(cy, cy, cx * cx));
#pragma unroll
        for (int c = 0; c < 4; c++) {
            float dot = fmaf(qz[c], cz, fmaf(qy[c], cy, qx[c] * cx));
            float d2 = (sqi[c] + sqj) - 2.f * dot;
            if (d2 <= tau[c]) {
                int ql = qg * 4 + c;
                int pos = atomicAdd(&scnt[ql], 1);
                if (pos < KNN)
                    spairs[ql * KNN + pos] = make_uint2(__float_as_uint(d2), (unsigned)j);
            }
        }
    }
    __syncthreads();

    // ---- tail: one thread per query ---------------------------------------
    if (tid < 128) {
        int q = tid;
        float bd[KNN]; int bi[KNN];
#pragma unroll
        for (int s = 0; s < KNN; s++) {
            uint2 p = spairs[q * KNN + s];
            bd[s] = __uint_as_float(p.x);
            bi[s] = (int)p.y;
        }
        // sort by (d2, idx) ascending == jax.lax.top_k order
#pragma unroll
        for (int a = 0; a < KNN - 1; a++)
#pragma unroll
            for (int b2 = 0; b2 < KNN - 1 - a; b2++) {
                bool sw = (bd[b2] > bd[b2 + 1]) ||
                          (bd[b2] == bd[b2 + 1] && bi[b2] > bi[b2 + 1]);
                float d_lo = sw ? bd[b2 + 1] : bd[b2];
                float d_hi = sw ? bd[b2] : bd[b2 + 1];
                int   i_lo = sw ? bi[b2 + 1] : bi[b2];
                int   i_hi = sw ? bi[b2] : bi[b2 + 1];
                bd[b2] = d_lo; bd[b2 + 1] = d_hi; bi[b2] = i_lo; bi[b2 + 1] = i_hi;
            }
        float xs[KNN], ys[KNN], zs[KNN];
#pragma unroll
        for (int s = 0; s < KNN; s++) {
            int j = bi[s];
            xs[s] = sx[j]; ys[s] = sy[j]; zs[s] = sz[j];
        }
        float nv[3];
        eig_normal3(xs, ys, zs, nv);
        int qg2 = chunk * 128 + q;
        float* dst = nrm + ((size_t)cloud * 8 + b) * 3 * NPTS;
        dst[0 * NPTS + qg2] = nv[0];
        dst[1 * NPTS + qg2] = nv[1];
        dst[2 * NPTS + qg2] = nv[2];
    }
}

__global__ __launch_bounds__(256) void loss_kernel(const float* __restrict__ nrm,
                                                   float* __restrict__ out) {
    const int n = 8 * 3 * NPTS;
    const float* a = nrm;
    const float* b = nrm + n;
    float acc = 0.f;
    for (int i = blockIdx.x * 256 + threadIdx.x; i < n; i += gridDim.x * 256) {
        float dd = a[i] - b[i];
        acc = fmaf(dd, dd, acc);
    }
#pragma unroll
    for (int off = 32; off > 0; off >>= 1) acc += __shfl_down(acc, off);
    __shared__ float wsum[4];
    int lane = threadIdx.x & 63, wv = threadIdx.x >> 6;
    if (lane == 0) wsum[wv] = acc;
    __syncthreads();
    if (threadIdx.x == 0) {
        float t = wsum[0] + wsum[1] + wsum[2] + wsum[3];
        atomicAdd(out, t * (1.f / (float)n));
    }
}

// ---------------- fallback (ws too small): R1-verified fused path -----------

extern __shared__ float4 spts_dyn[];

__device__ void compute_normal3(const float4* __restrict__ pts, int qi, float out[3]) {
    float4 q = pts[qi];
    float bd[KNN];
    int   bi[KNN];
#pragma unroll
    for (int s = 0; s < KNN; s++) { bd[s] = 3.4e38f; bi[s] = 0; }
    float worst = 3.4e38f;
    int wslot = 0;
    float sqi = q.w;

#pragma unroll 4
    for (int j = 0; j < NPTS; j++) {
        float4 cc = pts[j];
        float dot = fmaf(q.z, cc.z, fmaf(q.y, cc.y, q.x * cc.x));
        float d2 = (sqi + cc.w) - 2.f * dot;
        if (d2 < worst) {
#pragma unroll
            for (int s = 0; s < KNN; s++) { if (s == wslot) { bd[s] = d2; bi[s] = j; } }
            float w = bd[0]; int ws = 0;
#pragma unroll
            for (int s = 1; s < KNN; s++) { if (bd[s] > w) { w = bd[s]; ws = s; } }
            worst = w; wslot = ws;
        }
    }
#pragma unroll
    for (int a = 0; a < KNN - 1; a++)
#pragma unroll
        for (int b2 = 0; b2 < KNN - 1 - a; b2++) {
            bool sw = (bd[b2] > bd[b2 + 1]) ||
                      (bd[b2] == bd[b2 + 1] && bi[b2] > bi[b2 + 1]);
            float d_lo = sw ? bd[b2 + 1] : bd[b2];
            float d_hi = sw ? bd[b2] : bd[b2 + 1];
            int   i_lo = sw ? bi[b2 + 1] : bi[b2];
            int   i_hi = sw ? bi[b2] : bi[b2 + 1];
            bd[b2] = d_lo; bd[b2 + 1] = d_hi; bi[b2] = i_lo; bi[b2 + 1] = i_hi;
        }
    float xs[KNN], ys[KNN], zs[KNN];
#pragma unroll
    for (int s = 0; s < KNN; s++) {
        float4 cc = pts[bi[s]];
        xs[s] = cc.x; ys[s] = cc.y; zs[s] = cc.z;
    }
    eig_normal3(xs, ys, zs, out);
}

__global__ __launch_bounds__(256) void fused_kernel(const float* __restrict__ pred,
                                                    const float* __restrict__ gt,
                                                    float* __restrict__ out) {
    int bid = blockIdx.x;
    int b = bid >> 4;
    int chunk = bid & 15;
    int qi = chunk * 256 + threadIdx.x;
    float va[3], vb[3];

    const float* src = pred + (size_t)b * 3 * NPTS;
    for (int j = threadIdx.x; j < NPTS; j += 256) {
        float x = src[j], y = src[NPTS + j], z = src[2 * NPTS + j];
        spts_dyn[j] = make_float4(x, y, z, fmaf(z, z, fmaf(y, y, x * x)));
    }
    __syncthreads();
    compute_normal3(spts_dyn, qi, va);
    __syncthreads();

    src = gt + (size_t)b * 3 * NPTS;
    for (int j = threadIdx.x; j < NPTS; j += 256) {
        float x = src[j], y = src[NPTS + j], z = src[2 * NPTS + j];
        spts_dyn[j] = make_float4(x, y, z, fmaf(z, z, fmaf(y, y, x * x)));
    }
    __syncthreads();
    compute_normal3(spts_dyn, qi, vb);

    float d0 = va[0] - vb[0], d1 = va[1] - vb[1], d2 = va[2] - vb[2];
    float acc = fmaf(d2, d2, fmaf(d1, d1, d0 * d0));
#pragma unroll
    for (int off = 32; off > 0; off >>= 1) acc += __shfl_down(acc, off);
    __shared__ float wsum[4];
    int lane = threadIdx.x & 63, wv = threadIdx.x >> 6;
    if (lane == 0) wsum[wv] = acc;
    __syncthreads();
    if (threadIdx.x == 0) {
        float t = wsum[0] + wsum[1] + wsum[2] + wsum[3];
        atomicAdd(out, t * (1.f / (float)(8 * 3 * NPTS)));
    }
}

extern "C" void kernel_launch(void* const* d_in, const int* in_sizes, int n_in,
                              void* d_out, int out_size, void* d_ws, size_t ws_size,
                              hipStream_t stream) {
    (void)in_sizes; (void)n_in;
    const float* pred = (const float*)d_in[0];
    const float* gt   = (const float*)d_in[1];
    float* out = (float*)d_out;

    hipMemsetAsync(d_out, 0, (size_t)out_size * sizeof(float), stream);

    size_t need = (size_t)2 * 8 * 3 * NPTS * sizeof(float);   // 768 KB
    if (ws_size >= need) {
        float* nrm = (float*)d_ws;
        hipLaunchKernelGGL(normals_kernel, dim3(512), dim3(512), 0,
                           stream, pred, gt, nrm);
        hipLaunchKernelGGL(loss_kernel, dim3(96), dim3(256), 0, stream, nrm, out);
    } else {
        hipLaunchKernelGGL(fused_kernel, dim3(128), dim3(256), NPTS * sizeof(float4),
                           stream, pred, gt, out);
    }
}

// Round 4
// 247.024 us; speedup vs baseline: 3.1736x; 1.1013x over previous
//
#include <hip/hip_runtime.h>
#include <math.h>

#define NPTS 4096
#define KNN 10
#define CAP 40          // provable max pass-2 hits per query (10 groups x 4)

__device__ __forceinline__ float med3f(float a, float b, float c) {
    return __builtin_amdgcn_fmed3f(a, b, c);
}

// ---------------- LAPACK building blocks (f32, faithful to netlib) ----------
// Verified bit-exact vs numpy/LAPACK in R1-R3 (absmax 0.0). DO NOT TOUCH.

__device__ __forceinline__ float slapy2_(float x, float y) {
    float ax = fabsf(x), ay = fabsf(y);
    float w = fmaxf(ax, ay), z = fminf(ax, ay);
    if (z == 0.f) return w;
    float t = z / w;
    return w * sqrtf(1.f + t * t);
}

// LAPACK >= 3.10 slartg convention: c >= 0, r = sign(f)*d, s = g/r
__device__ __forceinline__ void slartg_(float f, float g, float* c, float* s, float* r) {
    if (g == 0.f) { *c = 1.f; *s = 0.f; *r = f; }
    else if (f == 0.f) { *c = 0.f; *s = copysignf(1.f, g); *r = fabsf(g); }
    else {
        float f1 = fabsf(f);
        float d = sqrtf(f * f + g * g);
        float rr = copysignf(d, f);
        *c = f1 / d;
        *s = g / rr;
        *r = rr;
    }
}

__device__ void slaev2_(float a, float b, float c,
                        float* rt1, float* rt2, float* cs1, float* sn1) {
    float sm = a + c;
    float df = a - c;
    float adf = fabsf(df);
    float tb = b + b;
    float ab = fabsf(tb);
    float acmx, acmn;
    if (fabsf(a) > fabsf(c)) { acmx = a; acmn = c; } else { acmx = c; acmn = a; }
    float rt;
    if (adf > ab)      { float t = ab / adf; rt = adf * sqrtf(1.f + t * t); }
    else if (adf < ab) { float t = adf / ab; rt = ab * sqrtf(1.f + t * t); }
    else               { rt = ab * sqrtf(2.f); }
    int sgn1;
    if (sm < 0.f) {
        *rt1 = 0.5f * (sm - rt); sgn1 = -1;
        *rt2 = (acmx / *rt1) * acmn - (b / *rt1) * b;
    } else if (sm > 0.f) {
        *rt1 = 0.5f * (sm + rt); sgn1 = 1;
        *rt2 = (acmx / *rt1) * acmn - (b / *rt1) * b;
    } else {
        *rt1 = 0.5f * rt; *rt2 = -0.5f * rt; sgn1 = 1;
    }
    int sgn2;
    float cs;
    if (df >= 0.f) { cs = df + rt; sgn2 = 1; } else { cs = df - rt; sgn2 = -1; }
    float acs = fabsf(cs);
    if (acs > ab) {
        float ct = -tb / cs;
        *sn1 = 1.f / sqrtf(1.f + ct * ct);
        *cs1 = ct * (*sn1);
    } else {
        if (ab == 0.f) { *cs1 = 1.f; *sn1 = 0.f; }
        else {
            float tn = -cs / tb;
            *cs1 = 1.f / sqrtf(1.f + tn * tn);
            *sn1 = tn * (*cs1);
        }
    }
    if (sgn1 == sgn2) { float tn = *cs1; *cs1 = -(*sn1); *sn1 = tn; }
}

// ssteqr for n=3, ICOMPZ='I' path
__device__ void steqr3_(float* d, float* e, float Z[3][3]) {
    const float eps    = 5.9604644775390625e-8f;  // 2^-24
    const float eps2   = eps * eps;
    const float safmin = 1.17549435e-38f;
    const int n = 3, nm1 = 2;
    const int nmaxit = 90;
    int jtot = 0, l1 = 1;
    int guard = 0;

    while (l1 <= n) {
        if (++guard > 600) break;
        if (l1 > 1) e[l1 - 2] = 0.f;
        int m = n;
        if (l1 <= nm1) {
            for (int mm = l1; mm <= nm1; ++mm) {
                float tst = fabsf(e[mm - 1]);
                if (tst == 0.f) { m = mm; break; }
                if (tst <= (sqrtf(fabsf(d[mm - 1])) * sqrtf(fabsf(d[mm]))) * eps) {
                    e[mm - 1] = 0.f; m = mm; break;
                }
            }
        }
        int l = l1, lsv = l1, lend = m, lendsv = m;
        l1 = m + 1;
        if (lend == l) continue;
        float anorm = 0.f;
        for (int i = l; i <= lend; i++) anorm = fmaxf(anorm, fabsf(d[i - 1]));
        for (int i = l; i <= lend - 1; i++) anorm = fmaxf(anorm, fabsf(e[i - 1]));
        if (anorm == 0.f) continue;
        if (fabsf(d[lend - 1]) < fabsf(d[l - 1])) { lend = lsv; l = lendsv; }

        if (lend > l) {
            for (;;) {
                if (++guard > 600) return;
                int m2 = lend;
                if (l != lend) {
                    for (int mm = l; mm <= lend - 1; ++mm) {
                        float tst = e[mm - 1] * e[mm - 1];
                        if (tst <= (eps2 * fabsf(d[mm - 1])) * fabsf(d[mm]) + safmin) { m2 = mm; break; }
                    }
                }
                if (m2 < lend) e[m2 - 1] = 0.f;
                float p = d[l - 1];
                if (m2 == l) {
                    d[l - 1] = p; l = l + 1;
                    if (l <= lend) continue;
                    break;
                }
                if (m2 == l + 1) {
                    float rt1, rt2, c, s;
                    slaev2_(d[l - 1], e[l - 1], d[l], &rt1, &rt2, &c, &s);
                    for (int i = 0; i < 3; i++) {
                        float t = Z[i][l];
                        Z[i][l]     = c * t - s * Z[i][l - 1];
                        Z[i][l - 1] = s * t + c * Z[i][l - 1];
                    }
                    d[l - 1] = rt1; d[l] = rt2; e[l - 1] = 0.f;
                    l += 2;
                    if (l <= lend) continue;
                    break;
                }
                if (jtot == nmaxit) break;
                jtot++;
                float g = (d[l] - p) / (2.f * e[l - 1]);
                float r = slapy2_(g, 1.f);
                g = d[m2 - 1] - p + e[l - 1] / (g + copysignf(r, g));
                float s = 1.f, c = 1.f;
                p = 0.f;
                float csv[2], snv[2];
                for (int i = m2 - 1; i >= l; --i) {
                    float f = s * e[i - 1];
                    float b = c * e[i - 1];
                    slartg_(g, f, &c, &s, &r);
                    if (i != m2 - 1) e[i] = r;
                    g = d[i] - p;
                    r = (d[i - 1] - g) * s + 2.f * c * b;
                    p = s * r;
                    d[i] = g + p;
                    g = c * r - b;
                    csv[i - l] = c; snv[i - l] = -s;
                }
                int nrot = m2 - l;
                for (int j = nrot; j >= 1; --j) {
                    float C = csv[j - 1], S = snv[j - 1];
                    for (int i = 0; i < 3; i++) {
                        float t = Z[i][l - 1 + j];
                        Z[i][l - 1 + j] = C * t - S * Z[i][l - 2 + j];
                        Z[i][l - 2 + j] = S * t + C * Z[i][l - 2 + j];
                    }
                }
                d[l - 1] = d[l - 1] - p;
                e[l - 1] = g;
            }
        } else {
            for (;;) {
                if (++guard > 600) return;
                int m2 = lend;
                if (l != lend) {
                    for (int mm = l; mm >= lend + 1; --mm) {
                        float tst = e[mm - 2] * e[mm - 2];
                        if (tst <= (eps2 * fabsf(d[mm - 1])) * fabsf(d[mm - 2]) + safmin) { m2 = mm; break; }
                    }
                }
                if (m2 > lend) e[m2 - 2] = 0.f;
                float p = d[l - 1];
                if (m2 == l) {
                    d[l - 1] = p; l = l - 1;
                    if (l >= lend) continue;
                    break;
                }
                if (m2 == l - 1) {
                    float rt1, rt2, c, s;
                    slaev2_(d[l - 2], e[l - 2], d[l - 1], &rt1, &rt2, &c, &s);
                    for (int i = 0; i < 3; i++) {
                        float t = Z[i][l - 1];
                        Z[i][l - 1] = c * t - s * Z[i][l - 2];
                        Z[i][l - 2] = s * t + c * Z[i][l - 2];
                    }
                    d[l - 2] = rt1; d[l - 1] = rt2; e[l - 2] = 0.f;
                    l -= 2;
                    if (l >= lend) continue;
                    break;
                }
                if (jtot == nmaxit) break;
                jtot++;
                float g = (d[l - 2] - p) / (2.f * e[l - 2]);
                float r = slapy2_(g, 1.f);
                g = d[m2 - 1] - p + e[l - 2] / (g + copysignf(r, g));
                float s = 1.f, c = 1.f;
                p = 0.f;
                float csv[2], snv[2];
                for (int i = m2; i <= l - 1; ++i) {
                    float f = s * e[i - 1];
                    float b = c * e[i - 1];
                    slartg_(g, f, &c, &s, &r);
                    if (i != m2) e[i - 2] = r;
                    g = d[i - 1] - p;
                    r = (d[i] - g) * s + 2.f * c * b;
                    p = s * r;
                    d[i - 1] = g + p;
                    g = c * r - b;
                    csv[i - m2] = c; snv[i - m2] = s;
                }
                int nrot = l - m2;
                for (int j = 1; j <= nrot; ++j) {
                    float C = csv[j - 1], S = snv[j - 1];
                    for (int i = 0; i < 3; i++) {
                        float t = Z[i][m2 - 1 + j];
                        Z[i][m2 - 1 + j] = C * t - S * Z[i][m2 - 2 + j];
                        Z[i][m2 - 2 + j] = S * t + C * Z[i][m2 - 2 + j];
                    }
                }
                d[l - 1] -= p;
                e[l - 2] = g;
            }
        }
    }
    for (int ii = 2; ii <= n; ++ii) {
        int i = ii - 1, k = i;
        float p = d[i - 1];
        for (int j = ii; j <= n; ++j) {
            if (d[j - 1] < p) { k = j; p = d[j - 1]; }
        }
        if (k != i) {
            d[k - 1] = d[i - 1]; d[i - 1] = p;
            for (int r2 = 0; r2 < 3; r2++) {
                float t = Z[r2][i - 1]; Z[r2][i - 1] = Z[r2][k - 1]; Z[r2][k - 1] = t;
            }
        }
    }
}

// cov -> sytrd -> steqr -> apply Q. Identical arithmetic to R1-R3.
__device__ void eig_normal3(const float xs[KNN], const float ys[KNN], const float zs[KNN],
                            float out[3]) {
    float mx = 0.f, my = 0.f, mz = 0.f;
#pragma unroll
    for (int s = 0; s < KNN; s++) { mx += xs[s]; my += ys[s]; mz += zs[s]; }
    mx /= 10.0f; my /= 10.0f; mz /= 10.0f;

    float c00 = 0.f, c10 = 0.f, c20 = 0.f, c11 = 0.f, c21 = 0.f, c22 = 0.f;
#pragma unroll
    for (int s = 0; s < KNN; s++) {
        float dx = xs[s] - mx, dy = ys[s] - my, dz = zs[s] - mz;
        c00 = fmaf(dx, dx, c00);
        c10 = fmaf(dy, dx, c10);
        c20 = fmaf(dz, dx, c20);
        c11 = fmaf(dy, dy, c11);
        c21 = fmaf(dz, dy, c21);
        c22 = fmaf(dz, dz, c22);
    }
    c00 /= 10.0f; c10 /= 10.0f; c20 /= 10.0f; c11 /= 10.0f; c21 /= 10.0f; c22 /= 10.0f;

    float alpha = c10, x2 = c20;
    float tau, v2, beta;
    float xnorm = fabsf(x2);
    if (xnorm == 0.f) { tau = 0.f; v2 = 0.f; beta = alpha; }
    else {
        beta = -copysignf(slapy2_(alpha, xnorm), alpha);
        tau = (beta - alpha) / beta;
        v2 = x2 / (alpha - beta);
    }
    float d[3], e[2];
    d[0] = c00;
    if (tau != 0.f) {
        float p0 = tau * (c11 + c21 * v2);
        float p1 = tau * (c21 + c22 * v2);
        float aw = -0.5f * tau * (p0 + p1 * v2);
        float w0 = p0 + aw;
        float w1 = p1 + aw * v2;
        d[1] = (c11 - w0) - w0;
        e[1] = (c21 - v2 * w0) - w1;
        d[2] = (c22 - v2 * w1) - w1 * v2;
        e[0] = beta;
    } else {
        d[1] = c11; d[2] = c22; e[0] = beta; e[1] = c21;
    }

    float Z[3][3] = {{1.f, 0.f, 0.f}, {0.f, 1.f, 0.f}, {0.f, 0.f, 1.f}};
    steqr3_(d, e, Z);

    float y0 = Z[0][0], y1 = Z[1][0], y2 = Z[2][0];
    if (tau != 0.f) {
        float t = tau * (y1 + v2 * y2);
        y1 = y1 - t;
        y2 = y2 - t * v2;
    }
    out[0] = y0; out[1] = y1; out[2] = y2;
}

// ---- sorted-desc merge across lanes: min(A_i,B_{9-i}) is a bitonic mountain;
// 15-CE bitonic desc network (pads -inf virtual at 10..15, no-op CEs skipped).
__device__ __forceinline__ void merge_round(float* v, int off) {
    float t[KNN];
#pragma unroll
    for (int i = 0; i < KNN; i++) t[i] = fminf(v[i], __shfl_xor(v[KNN - 1 - i], off));
#define CE(a, b) { float hi = fmaxf(t[a], t[b]); float lo = fminf(t[a], t[b]); t[a] = hi; t[b] = lo; }
    CE(0, 8) CE(1, 9)
    CE(0, 4) CE(1, 5) CE(2, 6) CE(3, 7)
    CE(0, 2) CE(1, 3) CE(4, 6) CE(5, 7)
    CE(0, 1) CE(2, 3) CE(4, 5) CE(6, 7) CE(8, 9)
#undef CE
#pragma unroll
    for (int i = 0; i < KNN; i++) v[i] = t[i];
}

// ---------------- one phase: stage cloud -> normals for 64 queries ----------
// 512 threads = 16 query-groups (Q=4) x 32 parts. Strip = 128 candidates,
// 32 groups of 4. Pass 1 builds tau' = 10th-smallest group-min (upper bound
// on true 10th-smallest d2). Pass 2 collects idx with d2 <= tau' (<=40,
// provable). Tail recomputes exact d2 and selects exact top-10 by (d2,idx).
__device__ void do_phase(const float* __restrict__ src, int chunk, int tid,
                         float2* sxy, float* sz, unsigned short* spairs, int* scnt,
                         float nv[3]) {
    // stage
    for (int j = tid; j < NPTS; j += 512) {
        float x = src[j], y = src[NPTS + j], z = src[2 * NPTS + j];
        sxy[j] = make_float2(x, y);
        sz[j] = z;
    }
    if (tid < 64) scnt[tid] = 0;
    __syncthreads();

    int part = tid & 31;
    int qg = tid >> 5;            // 0..15
    int ql0 = qg * 4;
    int q0 = chunk * 64 + ql0;

    float qx[4], qy[4], qz[4], sqi[4];
#pragma unroll
    for (int c = 0; c < 4; c++) {
        float2 a = sxy[q0 + c];
        float z = sz[q0 + c];
        qx[c] = a.x; qy[c] = a.y; qz[c] = z;
        sqi[c] = fmaf(z, z, fmaf(a.y, a.y, a.x * a.x));
    }

    // ---- pass 1: med3 chain over 4-candidate group minima ------------------
    float v[4][KNN + 1];
#pragma unroll
    for (int c = 0; c < 4; c++) {
#pragma unroll
        for (int s = 0; s < KNN; s++) v[c][s] = INFINITY;
        v[c][KNN] = -INFINITY;
    }

#pragma unroll 2
    for (int g = 0; g < 32; g++) {
        int jb = part + 128 * g;
        float m[4];
        {
            float2 a0 = sxy[jb], a1 = sxy[jb + 32];
            float z0 = sz[jb], z1 = sz[jb + 32];
            float w0 = fmaf(z0, z0, fmaf(a0.y, a0.y, a0.x * a0.x));
            float w1 = fmaf(z1, z1, fmaf(a1.y, a1.y, a1.x * a1.x));
#pragma unroll
            for (int c = 0; c < 4; c++) {
                float dot0 = fmaf(qz[c], z0, fmaf(qy[c], a0.y, qx[c] * a0.x));
                float d20 = (sqi[c] + w0) - 2.f * dot0;
                float dot1 = fmaf(qz[c], z1, fmaf(qy[c], a1.y, qx[c] * a1.x));
                float d21 = (sqi[c] + w1) - 2.f * dot1;
                m[c] = fminf(d20, d21);
            }
        }
        {
            float2 a0 = sxy[jb + 64], a1 = sxy[jb + 96];
            float z0 = sz[jb + 64], z1 = sz[jb + 96];
            float w0 = fmaf(z0, z0, fmaf(a0.y, a0.y, a0.x * a0.x));
            float w1 = fmaf(z1, z1, fmaf(a1.y, a1.y, a1.x * a1.x));
#pragma unroll
            for (int c = 0; c < 4; c++) {
                float dot0 = fmaf(qz[c], z0, fmaf(qy[c], a0.y, qx[c] * a0.x));
                float d20 = (sqi[c] + w0) - 2.f * dot0;
                float dot1 = fmaf(qz[c], z1, fmaf(qy[c], a1.y, qx[c] * a1.x));
                float d21 = (sqi[c] + w1) - 2.f * dot1;
                m[c] = fminf(m[c], fminf(d20, d21));
            }
        }
#pragma unroll
        for (int c = 0; c < 4; c++)
#pragma unroll
            for (int s = 0; s < KNN; s++) v[c][s] = med3f(m[c], v[c][s], v[c][s + 1]);
    }

    // ---- merge the 32 part-lists -> tau' = global 10th-smallest group-min --
    float tau[4];
#pragma unroll
    for (int c = 0; c < 4; c++) {
        merge_round(v[c], 1);
        merge_round(v[c], 2);
        merge_round(v[c], 4);
        merge_round(v[c], 8);
        merge_round(v[c], 16);
        tau[c] = v[c][0];
    }

    // ---- pass 2: collect idx with exact d2 <= tau' -------------------------
#pragma unroll 2
    for (int mm = 0; mm < 128; mm++) {
        int j = part + 32 * mm;
        float2 a = sxy[j];
        float z = sz[j];
        float w = fmaf(z, z, fmaf(a.y, a.y, a.x * a.x));
#pragma unroll
        for (int c = 0; c < 4; c++) {
            float dot = fmaf(qz[c], z, fmaf(qy[c], a.y, qx[c] * a.x));
            float d2 = (sqi[c] + w) - 2.f * dot;
            if (d2 <= tau[c]) {
                int ql = ql0 + c;
                int pos = atomicAdd(&scnt[ql], 1);
                if (pos < CAP) spairs[ql * CAP + pos] = (unsigned short)j;
            }
        }
    }
    __syncthreads();

    // ---- tail: exact top-10 by (d2, idx) from <=40 candidates --------------
    if (tid < 64) {
        int ql = tid;
        int qi = chunk * 64 + ql;
        float2 qa = sxy[qi];
        float qzz = sz[qi];
        float qw = fmaf(qzz, qzz, fmaf(qa.y, qa.y, qa.x * qa.x));
        int cnt = scnt[ql];
        if (cnt > CAP) cnt = CAP;

        float bd[KNN]; int bi_[KNN];
#pragma unroll
        for (int s = 0; s < KNN; s++) { bd[s] = 3.4e38f; bi_[s] = 0; }
        float worst = 3.4e38f;
        int wslot = 0;
        for (int t = 0; t < cnt; t++) {
            int j = spairs[ql * CAP + t];
            float2 a = sxy[j];
            float z = sz[j];
            float w = fmaf(z, z, fmaf(a.y, a.y, a.x * a.x));
            float dot = fmaf(qzz, z, fmaf(qa.y, a.y, qa.x * a.x));
            float d2 = (qw + w) - 2.f * dot;
            if (d2 < worst) {
#pragma unroll
                for (int s = 0; s < KNN; s++) { if (s == wslot) { bd[s] = d2; bi_[s] = j; } }
                float wm = bd[0]; int ws = 0;
#pragma unroll
                for (int s = 1; s < KNN; s++) { if (bd[s] > wm) { wm = bd[s]; ws = s; } }
                worst = wm; wslot = ws;
            }
        }
        // sort by (d2, idx) ascending == jax.lax.top_k order
#pragma unroll
        for (int a = 0; a < KNN - 1; a++)
#pragma unroll
            for (int b2 = 0; b2 < KNN - 1 - a; b2++) {
                bool sw = (bd[b2] > bd[b2 + 1]) ||
                          (bd[b2] == bd[b2 + 1] && bi_[b2] > bi_[b2 + 1]);
                float d_lo = sw ? bd[b2 + 1] : bd[b2];
                float d_hi = sw ? bd[b2] : bd[b2 + 1];
                int   i_lo = sw ? bi_[b2 + 1] : bi_[b2];
                int   i_hi = sw ? bi_[b2] : bi_[b2 + 1];
                bd[b2] = d_lo; bd[b2 + 1] = d_hi; bi_[b2] = i_lo; bi_[b2 + 1] = i_hi;
            }
        float xs[KNN], ys[KNN], zs[KNN];
#pragma unroll
        for (int s = 0; s < KNN; s++) {
            int j = bi_[s];
            float2 a = sxy[j];
            xs[s] = a.x; ys[s] = a.y; zs[s] = sz[j];
        }
        eig_normal3(xs, ys, zs, nv);
    }
    __syncthreads();   // protect LDS before next phase restages
}

// ---------------- fused kernel: both clouds + loss --------------------------
// grid = 8 batches x 64 chunks = 512 blocks x 512 threads. LDS 53.5 KB.

__global__ __launch_bounds__(512, 4) void fused_kernel(const float* __restrict__ pred,
                                                       const float* __restrict__ gt,
                                                       float* __restrict__ out) {
    __shared__ float2 sxy[NPTS];                 // 32 KB
    __shared__ float  sz[NPTS];                  // 16 KB
    __shared__ unsigned short spairs[64 * CAP];  // 5 KB
    __shared__ int scnt[64];

    int tid = threadIdx.x;
    int bid = blockIdx.x;
    int b = bid >> 6;
    int chunk = bid & 63;

    const float* pbase = pred + (size_t)b * 3 * NPTS;
    const float* gbase = gt + (size_t)b * 3 * NPTS;

    float va[3] = {0.f, 0.f, 0.f}, vb[3] = {0.f, 0.f, 0.f};
    do_phase(pbase, chunk, tid, sxy, sz, spairs, scnt, va);
    do_phase(gbase, chunk, tid, sxy, sz, spairs, scnt, vb);

    if (tid < 64) {   // wave 0 exactly
        float d0 = va[0] - vb[0], d1 = va[1] - vb[1], d2 = va[2] - vb[2];
        float acc = fmaf(d2, d2, fmaf(d1, d1, d0 * d0));
#pragma unroll
        for (int off = 32; off > 0; off >>= 1) acc += __shfl_down(acc, off);
        if (tid == 0) atomicAdd(out, acc * (1.f / (float)(8 * 3 * NPTS)));
    }
}

extern "C" void kernel_launch(void* const* d_in, const int* in_sizes, int n_in,
                              void* d_out, int out_size, void* d_ws, size_t ws_size,
                              hipStream_t stream) {
    (void)in_sizes; (void)n_in; (void)d_ws; (void)ws_size;
    const float* pred = (const float*)d_in[0];
    const float* gt   = (const float*)d_in[1];
    float* out = (float*)d_out;

    hipMemsetAsync(d_out, 0, (size_t)out_size * sizeof(float), stream);
    hipLaunchKernelGGL(fused_kernel, dim3(512), dim3(512), 0, stream, pred, gt, out);
}